// Round 6
// baseline (13.081 us; speedup 1.0000x reference)
//
#include <hip/hip_runtime.h>

// ---------------- quad DPP helpers (4-lane groups = one 16-node graph) ----------------
#define QP_XOR1 0xB1   // [1,0,3,2]
#define QP_XOR2 0x4E   // [2,3,0,1]

template<int CTRL>
__device__ __forceinline__ float dpp_f(float v) {
    return __builtin_bit_cast(float,
        __builtin_amdgcn_update_dpp(0, __builtin_bit_cast(int, v), CTRL, 0xF, 0xF, true));
}
__device__ __forceinline__ float qsum(float v) {    // sum over quad, result in all 4 lanes
    v += dpp_f<QP_XOR1>(v);
    v += dpp_f<QP_XOR2>(v);
    return v;
}

// partial bitonic merge: this lane's sorted-desc 4 with DPP partner's -> top-4 of union
template<int CTRL>
__device__ __forceinline__ void merge4(float& t0, float& t1, float& t2, float& t3) {
    const float p0 = dpp_f<CTRL>(t0), p1 = dpp_f<CTRL>(t1), p2 = dpp_f<CTRL>(t2), p3 = dpp_f<CTRL>(t3);
    const float c0 = fmaxf(t0, p3), c1 = fmaxf(t1, p2), c2 = fmaxf(t2, p1), c3 = fmaxf(t3, p0);
    const float d0 = fmaxf(c0, c2), d2 = fminf(c0, c2);
    const float d1 = fmaxf(c1, c3), d3 = fminf(c1, c3);
    t0 = fmaxf(d0, d1); t1 = fminf(d0, d1);
    t2 = fmaxf(d2, d3); t3 = fminf(d2, d3);
}

// collapsed GAT layer. Critical-path layout: max (5 ops) -> exps immediately;
// tau sort runs in parallel with exp latency; keep-mask applied afterwards.
__device__ __forceinline__ void gat4(const float s[4], const float xv[4], const float lx[4],
                                     const float4 ce, float& X, float& Lo, float& A) {
    float m = fmaxf(fmaxf(s[0], s[1]), fmaxf(s[2], s[3]));
    m = fmaxf(m, dpp_f<QP_XOR1>(m));
    m = fmaxf(m, dpp_f<QP_XOR2>(m));
    float e0 = __expf(s[0] - m), e1 = __expf(s[1] - m);
    float e2 = __expf(s[2] - m), e3 = __expf(s[3] - m);

    // tau = 4th largest of 16 (exact ties measure-zero on this data)
    const float a0 = fmaxf(s[0], s[1]), a1 = fminf(s[0], s[1]);
    const float a2 = fmaxf(s[2], s[3]), a3 = fminf(s[2], s[3]);
    const float b0 = fmaxf(a0, a2), b2 = fminf(a0, a2);
    const float b1 = fmaxf(a1, a3), b3 = fminf(a1, a3);
    float t0 = b0, t1 = fmaxf(b1, b2), t2 = fminf(b1, b2), t3 = b3;
    merge4<QP_XOR1>(t0, t1, t2, t3);
    merge4<QP_XOR2>(t0, t1, t2, t3);
    const float tau = t3;

    e0 = (s[0] >= tau) ? e0 : 0.f;
    e1 = (s[1] >= tau) ? e1 : 0.f;
    e2 = (s[2] >= tau) ? e2 : 0.f;
    e3 = (s[3] >= tau) ? e3 : 0.f;

    const float rd = __builtin_amdgcn_rcpf(qsum((e0 + e1) + (e2 + e3)));  // den in [1,4]
    X  = qsum(fmaf(e3, xv[3], fmaf(e2, xv[2], fmaf(e1, xv[1], e0 * xv[0])))) * rd;
    Lo = qsum(fmaf(e3, lx[3], fmaf(e2, lx[2], fmaf(e1, lx[1], e0 * lx[0])))) * rd;
    A  = qsum(fmaf(e3, ce.w,  fmaf(e2, ce.z,  fmaf(e1, ce.y,  e0 * ce.x)))) * rd;
}

// ---------------- LDS layout (float indices) ----------------
#define SW0   0      // w0 staged [j*32+k], 1024
#define SW1   1024
#define SEMBT 2048   // emb TRANSPOSED: embT[j*16+n], 512
#define SWIN  2560   // w_in, 64
#define SWOUT 2624   // w_out, 32
#define SA0H  2656   // a0[32..63]
#define SA1H  2688   // a1[32..63]
#define SBR   2720   // b_out + r_int[n], 16
#define SZERO 2736
#define G0    2752   // bases offset by 33 so G1/C0/C1 u-reads hit distinct banks
#define G1    2785
#define C0    2818
#define C1    2851
#define GS    2884
#define LDUMP 2917   // 256 scratch for idle lanes
#define LCST  3176   // [0..9] scalars; +16 tg0; +32 tg1; +48 tce0; +64 tce1; +80 tke
#define LDS_FLOATS 3272

// unified setup dot, both operands in LDS: L[dst] = sum_j L[uoff+j]*L[voff+j*vstr] + L[eoff]
__device__ __forceinline__ void job32L(float* L, int uoff, int voff, int vstr, int dst, int eoff) {
    float acc = 0.f;
    #pragma unroll
    for (int j = 0; j < 32; ++j) acc = fmaf(L[uoff + j], L[voff + j * vstr], acc);
    L[dst] = acc + L[eoff];
}

__global__ __launch_bounds__(256) void UltraSparseGNN_fused(
    const float* __restrict__ x,
    const float* __restrict__ w_in,
    const float* __restrict__ emb,
    const float* __restrict__ w0,
    const float* __restrict__ a0,
    const float* __restrict__ w1,
    const float* __restrict__ a1,
    const float* __restrict__ w_out,
    const float* __restrict__ b_out,
    const float* __restrict__ r_int,
    float* __restrict__ out,
    int total4)
{
    __shared__ __align__(16) float L[LDS_FLOATS];
    const int tid = threadIdx.x;

    // ---- phase A: stage ALL weights into LDS (single global-latency hit) ----
    ((float4*)&L[SW0])[tid] = ((const float4*)w0)[tid];
    ((float4*)&L[SW1])[tid] = ((const float4*)w1)[tid];
    if (tid < 128) {
        const float4 e = ((const float4*)emb)[tid];
        const int n = tid >> 3, j = (tid & 7) * 4;
        L[SEMBT + (j + 0) * 16 + n] = e.x;
        L[SEMBT + (j + 1) * 16 + n] = e.y;
        L[SEMBT + (j + 2) * 16 + n] = e.z;
        L[SEMBT + (j + 3) * 16 + n] = e.w;
    } else if (tid < 144) {
        ((float4*)&L[SWIN])[tid - 128] = ((const float4*)w_in)[tid - 128];
    } else if (tid < 152) {
        ((float4*)&L[SWOUT])[tid - 144] = ((const float4*)w_out)[tid - 144];
    } else if (tid < 160) {
        ((float4*)&L[SA0H])[tid - 152] = ((const float4*)a0)[(tid - 152) + 8];
    } else if (tid < 168) {
        ((float4*)&L[SA1H])[tid - 160] = ((const float4*)a1)[(tid - 160) + 8];
    } else if (tid < 184) {
        L[SBR + tid - 168] = r_int[tid - 168] + b_out[0];
    } else if (tid == 184) {
        L[SZERO] = 0.f;
    }
    __syncthreads();

    // ---- phase B1: g0, g1, c0, c1, tke, kx, kl (pure LDS) ----
    {
        int uoff = SWOUT, voff = SWOUT, vstr = 0, dst = LDUMP + tid, eoff = SZERO;
        if (tid < 32)        { voff = SW0 + tid;        vstr = 32; dst = G0 + tid; }
        else if (tid < 64)   { voff = SW1 + tid - 32;   vstr = 32; dst = G1 + tid - 32; }
        else if (tid < 96)   { uoff = SA0H; voff = SW0 + tid - 64; vstr = 32; dst = C0 + tid - 64; }
        else if (tid < 128)  { uoff = SA1H; voff = SW1 + tid - 96; vstr = 32; dst = C1 + tid - 96; }
        else if (tid < 144)  { voff = SEMBT + tid - 128; vstr = 16; dst = LCST + 80 + tid - 128; eoff = SBR + tid - 128; }
        else if (tid == 144) { voff = SWIN;     vstr = 2; dst = LCST + 4; }
        else if (tid == 145) { voff = SWIN + 1; vstr = 2; dst = LCST + 5; }
        job32L(L, uoff, voff, vstr, dst, eoff);
    }
    __syncthreads();

    // ---- phase B2: gs, tg0, tg1, tce1, scalars {a0c,b0c,a1c,b1c,C1X,C1L} ----
    {
        int uoff = SWOUT, voff = SWOUT, vstr = 0, dst = LDUMP + tid, eoff = SZERO;
        if (tid < 32)        { uoff = G1; voff = SW0 + tid; vstr = 32; dst = GS + tid; eoff = G0 + tid; }
        else if (tid < 48)   { uoff = C0; voff = SEMBT + tid - 32; vstr = 16; dst = LCST + 16 + tid - 32; }
        else if (tid < 64)   { uoff = C1; voff = SEMBT + tid - 48; vstr = 16; dst = LCST + 32 + tid - 48; }
        else if (tid < 80)   { uoff = G1; voff = SEMBT + tid - 64; vstr = 16; dst = LCST + 64 + tid - 64; }
        else if (tid == 80)  { uoff = C0; voff = SWIN;     vstr = 2; dst = LCST + 0; }
        else if (tid == 81)  { uoff = C0; voff = SWIN + 1; vstr = 2; dst = LCST + 1; }
        else if (tid == 82)  { uoff = C1; voff = SWIN;     vstr = 2; dst = LCST + 2; }
        else if (tid == 83)  { uoff = C1; voff = SWIN + 1; vstr = 2; dst = LCST + 3; }
        else if (tid == 84)  { uoff = G1; voff = SWIN;     vstr = 2; dst = LCST + 8; }
        else if (tid == 85)  { uoff = G1; voff = SWIN + 1; vstr = 2; dst = LCST + 9; }
        job32L(L, uoff, voff, vstr, dst, eoff);
    }
    __syncthreads();

    // ---- phase B3: tce0, C0X, C0L (need gs) ----
    {
        int voff = SWOUT, vstr = 0, dst = LDUMP + tid;
        if (tid < 16)        { voff = SEMBT + tid; vstr = 16; dst = LCST + 48 + tid; }
        else if (tid == 16)  { voff = SWIN;     vstr = 2; dst = LCST + 6; }
        else if (tid == 17)  { voff = SWIN + 1; vstr = 2; dst = LCST + 7; }
        job32L(L, GS, voff, vstr, dst, SZERO);
    }
    __syncthreads();

    // ---- main: 1 graph-quarter (float4) per thread ----
    const int idx = blockIdx.x * 256 + tid;
    if (idx >= total4) return;
    const int q = tid & 3;

    const float4 scA = *reinterpret_cast<const float4*>(&L[LCST + 0]); // A0c,B0c,A1c,B1c
    const float4 scB = *reinterpret_cast<const float4*>(&L[LCST + 4]); // KX,KL,C0X,C0L
    const float C1X = L[LCST + 8], C1L = L[LCST + 9];
    const float4 g0q  = *reinterpret_cast<const float4*>(&L[LCST + 16 + q * 4]);
    const float4 g1q  = *reinterpret_cast<const float4*>(&L[LCST + 32 + q * 4]);
    const float4 ce0q = *reinterpret_cast<const float4*>(&L[LCST + 48 + q * 4]);
    const float4 ce1q = *reinterpret_cast<const float4*>(&L[LCST + 64 + q * 4]);
    const float4 keq  = *reinterpret_cast<const float4*>(&L[LCST + 80 + q * 4]);

    const float4 xv4 = reinterpret_cast<const float4*>(x)[idx];
    float xv[4] = {xv4.x, xv4.y, xv4.z, xv4.w};
    float lx[4], s0[4], s1[4];
    const float g0a[4] = {g0q.x, g0q.y, g0q.z, g0q.w};
    const float g1a[4] = {g1q.x, g1q.y, g1q.z, g1q.w};
    #pragma unroll
    for (int i = 0; i < 4; ++i) {
        lx[i] = __logf(fmaxf(xv[i], 1e-6f));
        s0[i] = fmaf(scA.x, xv[i], fmaf(scA.y, lx[i], g0a[i]));
        s1[i] = fmaf(scA.z, xv[i], fmaf(scA.w, lx[i], g1a[i]));
    }

    float X0, L0, A0v, X1, L1, A1v;
    gat4(s0, xv, lx, ce0q, X0, L0, A0v);
    gat4(s1, xv, lx, ce1q, X1, L1, A1v);

    const float base = fmaf(X0, scB.z, fmaf(L0, scB.w, A0v)) + fmaf(X1, C1X, fmaf(L1, C1L, A1v));
    float4 o;
    o.x = fmaf(scB.x, xv[0], fmaf(scB.y, lx[0], keq.x + base));
    o.y = fmaf(scB.x, xv[1], fmaf(scB.y, lx[1], keq.y + base));
    o.z = fmaf(scB.x, xv[2], fmaf(scB.y, lx[2], keq.z + base));
    o.w = fmaf(scB.x, xv[3], fmaf(scB.y, lx[3], keq.w + base));
    reinterpret_cast<float4*>(out)[idx] = o;
}

extern "C" void kernel_launch(void* const* d_in, const int* in_sizes, int n_in,
                              void* d_out, int out_size, void* d_ws, size_t ws_size,
                              hipStream_t stream) {
    const float* x     = (const float*)d_in[0];
    const float* w_in  = (const float*)d_in[1];
    const float* emb   = (const float*)d_in[2];
    const float* w0    = (const float*)d_in[3];
    const float* a0    = (const float*)d_in[4];
    const float* w1    = (const float*)d_in[5];
    const float* a1    = (const float*)d_in[6];
    const float* w_out = (const float*)d_in[7];
    const float* b_out = (const float*)d_in[8];
    const float* r_int = (const float*)d_in[9];

    const int total  = in_sizes[0];            // B*T*N = 1048576 (multiple of 16)
    const int total4 = total >> 2;             // float4 count
    const int blocks = (total4 + 255) / 256;   // 1024
    UltraSparseGNN_fused<<<blocks, 256, 0, stream>>>(
        x, w_in, emb, w0, a0, w1, a1, w_out, b_out, r_int,
        (float*)d_out, total4);
}

// Round 7
// 12.787 us; speedup vs baseline: 1.0230x; 1.0230x over previous
//
#include <hip/hip_runtime.h>

// ---------------- quad DPP helpers (4-lane groups = one 16-node graph) ----------------
#define QP_XOR1 0xB1   // [1,0,3,2]
#define QP_XOR2 0x4E   // [2,3,0,1]

template<int CTRL>
__device__ __forceinline__ float dpp_f(float v) {
    return __builtin_bit_cast(float,
        __builtin_amdgcn_update_dpp(0, __builtin_bit_cast(int, v), CTRL, 0xF, 0xF, true));
}
__device__ __forceinline__ float qsum(float v) {    // sum over quad, result in all 4 lanes
    v += dpp_f<QP_XOR1>(v);
    v += dpp_f<QP_XOR2>(v);
    return v;
}

// partial bitonic merge: this lane's sorted-desc 4 with DPP partner's -> top-4 of union
template<int CTRL>
__device__ __forceinline__ void merge4(float& t0, float& t1, float& t2, float& t3) {
    const float p0 = dpp_f<CTRL>(t0), p1 = dpp_f<CTRL>(t1), p2 = dpp_f<CTRL>(t2), p3 = dpp_f<CTRL>(t3);
    const float c0 = fmaxf(t0, p3), c1 = fmaxf(t1, p2), c2 = fmaxf(t2, p1), c3 = fmaxf(t3, p0);
    const float d0 = fmaxf(c0, c2), d2 = fminf(c0, c2);
    const float d1 = fmaxf(c1, c3), d3 = fminf(c1, c3);
    t0 = fmaxf(d0, d1); t1 = fminf(d0, d1);
    t2 = fmaxf(d2, d3); t3 = fminf(d2, d3);
}

// collapsed GAT layer. Critical-path layout: group max (5 ops) -> exps issued
// immediately; the tau bitonic sort overlaps the exp latency; mask applied after.
__device__ __forceinline__ void gat4(const float s[4], const float xv[4], const float lx[4],
                                     const float4 ce, float& X, float& Lo, float& A) {
    float m = fmaxf(fmaxf(s[0], s[1]), fmaxf(s[2], s[3]));
    m = fmaxf(m, dpp_f<QP_XOR1>(m));
    m = fmaxf(m, dpp_f<QP_XOR2>(m));
    float e0 = __expf(s[0] - m), e1 = __expf(s[1] - m);
    float e2 = __expf(s[2] - m), e3 = __expf(s[3] - m);

    // tau = 4th largest of 16 (exact ties measure-zero on this data)
    const float a0 = fmaxf(s[0], s[1]), a1 = fminf(s[0], s[1]);
    const float a2 = fmaxf(s[2], s[3]), a3 = fminf(s[2], s[3]);
    const float b0 = fmaxf(a0, a2), b2 = fminf(a0, a2);
    const float b1 = fmaxf(a1, a3), b3 = fminf(a1, a3);
    float t0 = b0, t1 = fmaxf(b1, b2), t2 = fminf(b1, b2), t3 = b3;
    merge4<QP_XOR1>(t0, t1, t2, t3);
    merge4<QP_XOR2>(t0, t1, t2, t3);
    const float tau = t3;

    e0 = (s[0] >= tau) ? e0 : 0.f;
    e1 = (s[1] >= tau) ? e1 : 0.f;
    e2 = (s[2] >= tau) ? e2 : 0.f;
    e3 = (s[3] >= tau) ? e3 : 0.f;

    const float rd = __builtin_amdgcn_rcpf(qsum((e0 + e1) + (e2 + e3)));  // den in [1,4]
    X  = qsum(fmaf(e3, xv[3], fmaf(e2, xv[2], fmaf(e1, xv[1], e0 * xv[0])))) * rd;
    Lo = qsum(fmaf(e3, lx[3], fmaf(e2, lx[2], fmaf(e1, lx[1], e0 * lx[0])))) * rd;
    A  = qsum(fmaf(e3, ce.w,  fmaf(e2, ce.z,  fmaf(e1, ce.y,  e0 * ce.x)))) * rd;
}

// ---------------- LDS layout (floats) ----------------
#define U_WOUT 0
#define U_A0H  32
#define U_A1H  64
#define U_G0   96
#define U_G1   128
#define U_C0   160
#define U_C1   192
#define U_GS   224
#define LBR    256   // 16: b_out + r_int[n]
#define LZERO  272
#define LDUMP  288   // 256 scratch slots for idle lanes
#define LCST   544   // [0..9] scalars; +16 tg0; +32 tg1; +48 tce0; +64 tce1; +80 tke
#define LDS_FLOATS 704

// unified setup dot: L[dst] = sum_j L[uoff+j] * vb[j*vstr]  + L[eoff]
__device__ __forceinline__ void job32(float* L, int uoff, const float* __restrict__ vb,
                                      int vstr, int dst, int eoff) {
    float acc = 0.f;
    #pragma unroll
    for (int j = 0; j < 32; ++j) acc = fmaf(L[uoff + j], vb[j * vstr], acc);
    L[dst] = acc + L[eoff];
}

__device__ __forceinline__ void eval_graph(
    const float4 xv4, const float4 g0q, const float4 g1q,
    const float4 ce0q, const float4 ce1q, const float4 keq,
    float A0c, float B0c, float A1c, float B1c,
    float KX, float KL, float C0X, float C0L, float C1X, float C1L,
    float4& o)
{
    float xv[4] = {xv4.x, xv4.y, xv4.z, xv4.w};
    float lx[4], s0[4], s1[4];
    const float g0a[4] = {g0q.x, g0q.y, g0q.z, g0q.w};
    const float g1a[4] = {g1q.x, g1q.y, g1q.z, g1q.w};
    #pragma unroll
    for (int i = 0; i < 4; ++i) {
        lx[i] = __logf(fmaxf(xv[i], 1e-6f));
        s0[i] = fmaf(A0c, xv[i], fmaf(B0c, lx[i], g0a[i]));
        s1[i] = fmaf(A1c, xv[i], fmaf(B1c, lx[i], g1a[i]));
    }
    float X0, L0, A0v, X1, L1, A1v;
    gat4(s0, xv, lx, ce0q, X0, L0, A0v);
    gat4(s1, xv, lx, ce1q, X1, L1, A1v);
    const float base = fmaf(X0, C0X, fmaf(L0, C0L, A0v)) + fmaf(X1, C1X, fmaf(L1, C1L, A1v));
    o.x = fmaf(KX, xv[0], fmaf(KL, lx[0], keq.x + base));
    o.y = fmaf(KX, xv[1], fmaf(KL, lx[1], keq.y + base));
    o.z = fmaf(KX, xv[2], fmaf(KL, lx[2], keq.z + base));
    o.w = fmaf(KX, xv[3], fmaf(KL, lx[3], keq.w + base));
}

__global__ __launch_bounds__(256) void UltraSparseGNN_fused(
    const float* __restrict__ x,
    const float* __restrict__ w_in,
    const float* __restrict__ emb,
    const float* __restrict__ w0,
    const float* __restrict__ a0,
    const float* __restrict__ w1,
    const float* __restrict__ a1,
    const float* __restrict__ w_out,
    const float* __restrict__ b_out,
    const float* __restrict__ r_int,
    float* __restrict__ out,
    int total4, int half)
{
    __shared__ __align__(16) float L[LDS_FLOATS];
    const int tid = threadIdx.x;

    // ---- hoisted x loads: HBM latency overlaps the whole prologue ----
    const int tA  = blockIdx.x * 256 + tid;
    const bool doA = (tA < total4);
    const int tBi = tA + half;
    const bool doB = (tBi < total4);
    const int tAc = doA ? tA : 0;
    const int tBc = doB ? tBi : tAc;
    const float4 xvA = reinterpret_cast<const float4*>(x)[tAc];
    const float4 xvB = reinterpret_cast<const float4*>(x)[tBc];

    // ---- stage small u-vectors (parallel, one masked set) ----
    if (tid < 32)        L[U_WOUT + tid]      = w_out[tid];
    else if (tid < 64)   L[U_A0H + tid - 32]  = a0[32 + tid - 32];
    else if (tid < 96)   L[U_A1H + tid - 64]  = a1[32 + tid - 64];
    else if (tid < 112)  L[LBR + tid - 96]    = r_int[tid - 96] + b_out[0];
    else if (tid == 112) L[LZERO]             = 0.f;
    __syncthreads();

    // ---- phase B1: g0, g1, c0, c1, tke, kx, kl (all concurrent, one uniform loop) ----
    {
        int uoff = U_WOUT, vstr = 0, dst = LDUMP + tid, eoff = LZERO;
        const float* vb = w0;
        if (tid < 32)        { vb = w0 + tid;              vstr = 32; dst = U_G0 + tid; }
        else if (tid < 64)   { vb = w1 + (tid - 32);       vstr = 32; dst = U_G1 + (tid - 32); }
        else if (tid < 96)   { uoff = U_A0H; vb = w0 + (tid - 64); vstr = 32; dst = U_C0 + (tid - 64); }
        else if (tid < 128)  { uoff = U_A1H; vb = w1 + (tid - 96); vstr = 32; dst = U_C1 + (tid - 96); }
        else if (tid < 144)  { vb = emb + (tid - 128) * 32; vstr = 1; dst = LCST + 80 + (tid - 128); eoff = LBR + (tid - 128); }
        else if (tid == 144) { vb = w_in;     vstr = 2; dst = LCST + 4; }   // kx
        else if (tid == 145) { vb = w_in + 1; vstr = 2; dst = LCST + 5; }   // kl
        job32(L, uoff, vb, vstr, dst, eoff);
    }
    __syncthreads();

    // ---- phase B2: gs, tg0, tg1, tce1, scalars 0-3,8,9 ----
    {
        int uoff = U_G1, vstr = 0, dst = LDUMP + tid, eoff = LZERO;
        const float* vb = w0;
        if (tid < 32)        { vb = w0 + tid; vstr = 32; dst = U_GS + tid; eoff = U_G0 + tid; }
        else if (tid < 48)   { uoff = U_C0; vb = emb + (tid - 32) * 32; vstr = 1; dst = LCST + 16 + (tid - 32); }
        else if (tid < 64)   { uoff = U_C1; vb = emb + (tid - 48) * 32; vstr = 1; dst = LCST + 32 + (tid - 48); }
        else if (tid < 80)   { vb = emb + (tid - 64) * 32; vstr = 1; dst = LCST + 64 + (tid - 64); }
        else if (tid == 80)  { uoff = U_C0; vb = w_in;     vstr = 2; dst = LCST + 0; }
        else if (tid == 81)  { uoff = U_C0; vb = w_in + 1; vstr = 2; dst = LCST + 1; }
        else if (tid == 82)  { uoff = U_C1; vb = w_in;     vstr = 2; dst = LCST + 2; }
        else if (tid == 83)  { uoff = U_C1; vb = w_in + 1; vstr = 2; dst = LCST + 3; }
        else if (tid == 84)  { vb = w_in;     vstr = 2; dst = LCST + 8; }
        else if (tid == 85)  { vb = w_in + 1; vstr = 2; dst = LCST + 9; }
        job32(L, uoff, vb, vstr, dst, eoff);
    }
    __syncthreads();

    // ---- phase B3: tce0, C0X, C0L (need gs) ----
    {
        int vstr = 0, dst = LDUMP + tid;
        const float* vb = w0;
        if (tid < 16)        { vb = emb + tid * 32; vstr = 1; dst = LCST + 48 + tid; }
        else if (tid == 16)  { vb = w_in;     vstr = 2; dst = LCST + 6; }
        else if (tid == 17)  { vb = w_in + 1; vstr = 2; dst = LCST + 7; }
        job32(L, U_GS, vb, vstr, dst, LZERO);
    }
    __syncthreads();

    // ---- main: 2 graphs per thread, same quad position q (tables shared) ----
    if (!doA) return;
    const int q = tid & 3;

    const float4 scA = *reinterpret_cast<const float4*>(&L[LCST + 0]); // A0c,B0c,A1c,B1c
    const float4 scB = *reinterpret_cast<const float4*>(&L[LCST + 4]); // KX,KL,C0X,C0L
    const float C1X = L[LCST + 8], C1L = L[LCST + 9];
    const float4 g0q  = *reinterpret_cast<const float4*>(&L[LCST + 16 + q * 4]);
    const float4 g1q  = *reinterpret_cast<const float4*>(&L[LCST + 32 + q * 4]);
    const float4 ce0q = *reinterpret_cast<const float4*>(&L[LCST + 48 + q * 4]);
    const float4 ce1q = *reinterpret_cast<const float4*>(&L[LCST + 64 + q * 4]);
    const float4 keq  = *reinterpret_cast<const float4*>(&L[LCST + 80 + q * 4]);

    float4 oA, oB;
    eval_graph(xvA, g0q, g1q, ce0q, ce1q, keq,
               scA.x, scA.y, scA.z, scA.w, scB.x, scB.y, scB.z, scB.w, C1X, C1L, oA);
    eval_graph(xvB, g0q, g1q, ce0q, ce1q, keq,
               scA.x, scA.y, scA.z, scA.w, scB.x, scB.y, scB.z, scB.w, C1X, C1L, oB);

    reinterpret_cast<float4*>(out)[tA] = oA;
    if (doB) reinterpret_cast<float4*>(out)[tBi] = oB;
}

extern "C" void kernel_launch(void* const* d_in, const int* in_sizes, int n_in,
                              void* d_out, int out_size, void* d_ws, size_t ws_size,
                              hipStream_t stream) {
    const float* x     = (const float*)d_in[0];
    const float* w_in  = (const float*)d_in[1];
    const float* emb   = (const float*)d_in[2];
    const float* w0    = (const float*)d_in[3];
    const float* a0    = (const float*)d_in[4];
    const float* w1    = (const float*)d_in[5];
    const float* a1    = (const float*)d_in[6];
    const float* w_out = (const float*)d_in[7];
    const float* b_out = (const float*)d_in[8];
    const float* r_int = (const float*)d_in[9];

    const int total  = in_sizes[0];                 // B*T*N = 1048576 (mult of 16)
    const int total4 = total >> 2;                  // float4 count (mult of 4)
    const int half   = (((total4 + 1) >> 1) + 3) & ~3;  // mult of 4 so quad pos matches
    const int blocks = (half + 255) / 256;          // 512 for the bench shape
    UltraSparseGNN_fused<<<blocks, 256, 0, stream>>>(
        x, w_in, emb, w0, a0, w1, a1, w_out, b_out, r_int,
        (float*)d_out, total4, half);
}